// Round 3
// baseline (1024.791 us; speedup 1.0000x reference)
//
#include <hip/hip_runtime.h>
#include <hip/hip_bf16.h>

#define B_ 2
#define L_ 4800
#define S_ 4800
#define C_ 256
#define BLS ((size_t)B_ * L_ * S_)

constexpr float kLOG2E = 1.4426950408889634f;

typedef __bf16 bf16x8 __attribute__((ext_vector_type(8)));
typedef float f32x4 __attribute__((ext_vector_type(4)));

static __device__ __forceinline__ f32x4 mfma16(bf16x8 a, bf16x8 b, f32x4 c) {
    return __builtin_amdgcn_mfma_f32_16x16x32_bf16(a, b, c, 0, 0, 0);
}

// load 8 contiguous fp32, round-to-nearest-even convert to bf16x8
static __device__ __forceinline__ bf16x8 load_cvt8(const float* __restrict__ p) {
    float4 a = *(const float4*)p;
    float4 b = *(const float4*)(p + 4);
    bf16x8 r;
    r[0] = (__bf16)a.x; r[1] = (__bf16)a.y; r[2] = (__bf16)a.z; r[3] = (__bf16)a.w;
    r[4] = (__bf16)b.x; r[5] = (__bf16)b.y; r[6] = (__bf16)b.z; r[7] = (__bf16)b.w;
    return r;
}

// ---------------- K1: projection f = (x @ W^T + bias) / 16, bf16 out ----------------
// inputs fp32. grid (150, 16, 2), block 256. z selects feat_c0->f0 or feat_c1->f1.
__global__ __launch_bounds__(256) void proj_kernel(
    const float* __restrict__ x0, const float* __restrict__ x1,
    const float* __restrict__ W, const float* __restrict__ bias,
    __hip_bfloat16* __restrict__ y0, __hip_bfloat16* __restrict__ y1) {
    const float* __restrict__ x = (blockIdx.z == 0) ? x0 : x1;
    __hip_bfloat16* __restrict__ y = (blockIdx.z == 0) ? y0 : y1;

    int lane = threadIdx.x & 63, wid = threadIdx.x >> 6;
    int m = lane & 15, q = lane >> 4;
    int r0 = blockIdx.x * 64 + wid * 16;
    int c0 = blockIdx.y * 16;

    f32x4 acc = {0.f, 0.f, 0.f, 0.f};
    for (int kk = 0; kk < 8; ++kk) {
        bf16x8 a = load_cvt8(x + (size_t)(r0 + m) * C_ + kk * 32 + q * 8);
        bf16x8 b = load_cvt8(W + (size_t)(c0 + m) * C_ + kk * 32 + q * 8);
        acc = mfma16(a, b, acc);
    }
    float bv = bias[c0 + m];
#pragma unroll
    for (int i = 0; i < 4; ++i) {
        int row = q * 4 + i;  // C/D mapping: col = lane&15, row = (lane>>4)*4 + i
        y[(size_t)(r0 + row) * C_ + c0 + m] = __float2bfloat16((acc[i] + bv) * 0.0625f);
    }
}

// ---------------- K2: sim = (f0 @ f1^T) * 10, fp32 out ----------------
// grid (75, 75, 2), block 256 (4 waves, each 32x32 of the 64x64 tile).
__global__ __launch_bounds__(256) void sim_kernel(
    const __hip_bfloat16* __restrict__ f0, const __hip_bfloat16* __restrict__ f1,
    float* __restrict__ sim) {
    int b = blockIdx.z;
    int lane = threadIdx.x & 63, wid = threadIdx.x >> 6;
    int wm = wid & 1, wn = wid >> 1;
    int r0 = blockIdx.x * 64 + wm * 32;
    int c0 = blockIdx.y * 64 + wn * 32;
    int mi = lane & 15, q = lane >> 4;

    const __hip_bfloat16* __restrict__ A = f0 + (size_t)b * L_ * C_;
    const __hip_bfloat16* __restrict__ Bp = f1 + (size_t)b * S_ * C_;

    f32x4 acc[2][2] = {};
    for (int kk = 0; kk < 8; ++kk) {
        int ko = kk * 32 + q * 8;
        bf16x8 a0 = *(const bf16x8*)(A + (size_t)(r0 + mi) * C_ + ko);
        bf16x8 a1 = *(const bf16x8*)(A + (size_t)(r0 + 16 + mi) * C_ + ko);
        bf16x8 b0 = *(const bf16x8*)(Bp + (size_t)(c0 + mi) * C_ + ko);
        bf16x8 b1 = *(const bf16x8*)(Bp + (size_t)(c0 + 16 + mi) * C_ + ko);
        acc[0][0] = mfma16(a0, b0, acc[0][0]);
        acc[0][1] = mfma16(a0, b1, acc[0][1]);
        acc[1][0] = mfma16(a1, b0, acc[1][0]);
        acc[1][1] = mfma16(a1, b1, acc[1][1]);
    }
    float* __restrict__ simb = sim + (size_t)b * L_ * S_;
#pragma unroll
    for (int tm = 0; tm < 2; ++tm)
#pragma unroll
        for (int tn = 0; tn < 2; ++tn)
#pragma unroll
            for (int i = 0; i < 4; ++i) {
                int gr = r0 + tm * 16 + q * 4 + i;
                int gc = c0 + tn * 16 + mi;
                simb[(size_t)gr * S_ + gc] = acc[tm][tn][i] * 10.0f;
            }
}

static __device__ __forceinline__ void online_update(float v, float& m, float& z) {
    if (v <= m) {
        z += exp2f((v - m) * kLOG2E);
    } else {
        z = z * exp2f((m - v) * kLOG2E) + 1.0f;
        m = v;
    }
}

static __device__ __forceinline__ void merge_mz(float& m1, float& z1, float m2, float z2) {
    float M = fmaxf(m1, m2);
    z1 = z1 * exp2f((m1 - M) * kLOG2E) + z2 * exp2f((m2 - M) * kLOG2E);
    m1 = M;
}

// ---------------- K3a: row stats. grid 9600 blocks, block 256 ----------------
__global__ __launch_bounds__(256) void row_stats_kernel(
    const float* __restrict__ sim, float* __restrict__ rowM, float* __restrict__ rowZ) {
    int rg = blockIdx.x;  // b*L + l
    const float* __restrict__ p = sim + (size_t)rg * S_;
    int t = threadIdx.x;
    float m = -1e30f, z = 0.f;
    for (int s = t; s < S_; s += 256) online_update(p[s], m, z);

    __shared__ float sm[256], sz[256];
    sm[t] = m; sz[t] = z;
    __syncthreads();
    for (int off = 128; off; off >>= 1) {
        if (t < off) {
            float m1 = sm[t], z1 = sz[t];
            merge_mz(m1, z1, sm[t + off], sz[t + off]);
            sm[t] = m1; sz[t] = z1;
        }
        __syncthreads();
    }
    if (t == 0) { rowM[rg] = sm[0]; rowZ[rg] = sz[0]; }
}

// ---------------- K3b: column partial stats. grid (19, 16, B), block 256 ----------------
__global__ __launch_bounds__(256) void col_part_kernel(
    const float* __restrict__ sim, float* __restrict__ colPM, float* __restrict__ colPZ) {
    int s = blockIdx.x * 256 + threadIdx.x;
    if (s >= S_) return;
    int lc = blockIdx.y, b = blockIdx.z;
    const float* __restrict__ base = sim + ((size_t)b * L_ + (size_t)lc * 300) * S_;
    float m = -1e30f, z = 0.f;
    for (int l = 0; l < 300; ++l) online_update(base[(size_t)l * S_ + s], m, z);
    size_t o = (size_t)lc * (B_ * S_) + (size_t)b * S_ + s;
    colPM[o] = m; colPZ[o] = z;
}

// ---------------- K3c: reduce 16 column partials ----------------
__global__ __launch_bounds__(256) void col_reduce_kernel(
    const float* __restrict__ colPM, const float* __restrict__ colPZ,
    float* __restrict__ colM, float* __restrict__ colZ) {
    int idx = blockIdx.x * 256 + threadIdx.x;
    if (idx >= B_ * S_) return;
    float m = -1e30f, z = 0.f;
    for (int c = 0; c < 16; ++c)
        merge_mz(m, z, colPM[(size_t)c * (B_ * S_) + idx], colPZ[(size_t)c * (B_ * S_) + idx]);
    colM[idx] = m; colZ[idx] = z;
}

// ---------------- K4: final outputs (fp32). grid (19, 9600), block 256 ----------------
__global__ __launch_bounds__(256) void final_kernel(
    const float* __restrict__ sim,
    const float* __restrict__ rowM, const float* __restrict__ rowZ,
    const float* __restrict__ colM, const float* __restrict__ colZ,
    const int* __restrict__ ph0, const int* __restrict__ pw0,
    const int* __restrict__ ph1, const int* __restrict__ pw1,
    float* __restrict__ out) {
    int s = blockIdx.x * 256 + threadIdx.x;
    if (s >= S_) return;
    int rg = blockIdx.y;          // b*L + l
    int b = rg / L_;
    int l = rg - b * L_;

    int h0 = ph0[0], w0 = pw0[0], h1 = ph1[0], w1 = pw1[0];

    float v = sim[(size_t)rg * S_ + s];
    float rm = rowM[rg], rz = rowZ[rg];
    float cm = colM[(size_t)b * S_ + s], cz = colZ[(size_t)b * S_ + s];

    float conf0 = exp2f((v - rm) * kLOG2E) / rz;
    float conf1 = exp2f((v - cm) * kLOG2E) / cz;

    int i0 = l / w0, j0 = l - i0 * w0;
    bool okl = (i0 >= 2) & (i0 < h0 - 2) & (j0 >= 2) & (j0 < w0 - 2);
    int i1 = s / w1, j1 = s - i1 * w1;
    bool oks = (i1 >= 2) & (i1 < h1 - 2) & (j1 >= 2) & (j1 < w1 - 2);

    bool mk = (((conf0 > 0.2f) && (v == rm)) || ((conf1 > 0.2f) && (v == cm))) && okl && oks;
    float mc = mk ? fmaxf(conf0, conf1) : 0.f;

    size_t o = (size_t)rg * S_ + s;
    out[o] = conf0;
    out[o + BLS] = conf1;
    out[o + 2 * BLS] = mc;
}

extern "C" void kernel_launch(void* const* d_in, const int* in_sizes, int n_in,
                              void* d_out, int out_size, void* d_ws, size_t ws_size,
                              hipStream_t stream) {
    const float* feat0 = (const float*)d_in[0];
    const float* feat1 = (const float*)d_in[1];
    const float* W = (const float*)d_in[2];
    const float* bias = (const float*)d_in[3];
    const int* ph0 = (const int*)d_in[4];
    const int* pw0 = (const int*)d_in[5];
    const int* ph1 = (const int*)d_in[6];
    const int* pw1 = (const int*)d_in[7];
    float* out = (float*)d_out;

    char* ws = (char*)d_ws;
    size_t off = 0;
    auto alloc = [&](size_t bytes) { char* p = ws + off; off = (off + bytes + 255) & ~(size_t)255; return p; };
    __hip_bfloat16* f0 = (__hip_bfloat16*)alloc((size_t)B_ * L_ * C_ * 2);
    __hip_bfloat16* f1 = (__hip_bfloat16*)alloc((size_t)B_ * S_ * C_ * 2);
    float* sim = (float*)alloc(BLS * 4);
    float* rowM = (float*)alloc((size_t)B_ * L_ * 4);
    float* rowZ = (float*)alloc((size_t)B_ * L_ * 4);
    float* colPM = (float*)alloc((size_t)16 * B_ * S_ * 4);
    float* colPZ = (float*)alloc((size_t)16 * B_ * S_ * 4);
    float* colM = (float*)alloc((size_t)B_ * S_ * 4);
    float* colZ = (float*)alloc((size_t)B_ * S_ * 4);
    (void)ws_size; (void)in_sizes; (void)n_in; (void)out_size;

    proj_kernel<<<dim3(150, 16, 2), 256, 0, stream>>>(feat0, feat1, W, bias, f0, f1);
    sim_kernel<<<dim3(75, 75, 2), 256, 0, stream>>>(f0, f1, sim);
    row_stats_kernel<<<dim3(B_ * L_), 256, 0, stream>>>(sim, rowM, rowZ);
    col_part_kernel<<<dim3(19, 16, B_), 256, 0, stream>>>(sim, colPM, colPZ);
    col_reduce_kernel<<<dim3((B_ * S_ + 255) / 256), 256, 0, stream>>>(colPM, colPZ, colM, colZ);
    final_kernel<<<dim3(19, B_ * L_), 256, 0, stream>>>(sim, rowM, rowZ, colM, colZ,
                                                        ph0, pw0, ph1, pw1, out);
}